// Round 11
// baseline (1561.383 us; speedup 1.0000x reference)
//
#include <hip/hip_runtime.h>
#include <hip/hip_bf16.h>

#define B_  4096
#define T_  255
#define V_  32000
#define E_  64
#define H_  64
#define D1_ 32

#define NCT           2000   // V/16 col-tiles
#define NCHUNK        10
#define CT_PER_CHUNK  200    // NCT / NCHUNK
#define CT_PER_WAVE   50     // CT_PER_CHUNK / 4 waves

#define P1_REPS 32           // calibration: p1 dispatch = 32*p1 (visible >300us)
#define P2_REPS 4            // calibration: p2 dispatch = 4*p2
// total_R11 = total_R10 + 31*p1 + 3*p2 ; both idempotent -> bit-exact output.

typedef __attribute__((ext_vector_type(8))) short bf16x8;   // 8 bf16 = 4 VGPR
typedef __attribute__((ext_vector_type(4))) float f32x4;

__device__ __forceinline__ ushort f2bf(float f) {
    __hip_bfloat16 h = __float2bfloat16(f);   // RNE
    return *reinterpret_cast<ushort*>(&h);
}
__device__ __forceinline__ float fast_sigmoid(float x) {
    return __builtin_amdgcn_rcpf(1.f + __expf(-x));
}
// tanh with the 2x folded into prescaled weights (g gate scaled by 2.0):
__device__ __forceinline__ float fast_tanh_pre(float y) {
    return 1.f - 2.f * __builtin_amdgcn_rcpf(1.f + __expf(y));
}
__device__ __forceinline__ float fast_tanh(float x) {
    return 1.f - 2.f * __builtin_amdgcn_rcpf(1.f + __expf(2.f * x));
}

// Swizzled byte offset in a [16 rows][64 bf16] (128 B/row) h-tile.
__device__ __forceinline__ int hswz(int row, int colb) {
    return row * 128 + (colb ^ ((row & 7) << 4));
}

// ---------------------------------------------------------------------------
// Kernel 0 (merged): blocks [0,1000): emb fp32->bf16 ; [1000,1500): W2 repack.
// ---------------------------------------------------------------------------
__global__ __launch_bounds__(256)
void prep_kernel(const float* __restrict__ emb, ushort* __restrict__ emb_bf,
                 const float* __restrict__ W2,  ushort* __restrict__ w2p)
{
    if (blockIdx.x < 1000) {
        int i = blockIdx.x * 256 + threadIdx.x;      // over V*64/8 = 256000
        const float4 a = ((const float4*)emb)[i * 2];
        const float4 b = ((const float4*)emb)[i * 2 + 1];
        ushort t[8] = { f2bf(a.x), f2bf(a.y), f2bf(a.z), f2bf(a.w),
                        f2bf(b.x), f2bf(b.y), f2bf(b.z), f2bf(b.w) };
        *(ushort4*)(&emb_bf[i * 8])     = *(ushort4*)(&t[0]);
        *(ushort4*)(&emb_bf[i * 8 + 4]) = *(ushort4*)(&t[4]);
    } else {
        int t = (blockIdx.x - 1000) * 256 + threadIdx.x;   // over NCT*64
        if (t >= NCT * 64) return;
        int ct = t >> 6, l = t & 63;
        int kbase = (l >> 4) * 8, c = ct * 16 + (l & 15);
        ushort tmp[8];
        #pragma unroll
        for (int i = 0; i < 8; ++i)
            tmp[i] = f2bf(W2[(kbase + i) * V_ + c]);
        *(ushort4*)(&w2p[t * 8])     = *(ushort4*)(&tmp[0]);
        *(ushort4*)(&w2p[t * 8 + 4]) = *(ushort4*)(&tmp[4]);
    }
}

// ===========================================================================
// LSTM — byte-identical to R10 (dual-slot x pipeline + fused head1 epilogue).
// ===========================================================================
__global__ __launch_bounds__(256)
void lstm_mfma_kernel(const int* __restrict__ idx,
                      const ushort* __restrict__ emb_bf,
                      const float* __restrict__ Wx,
                      const float* __restrict__ Wh,
                      const float* __restrict__ b,
                      const float* __restrict__ W1,
                      const float* __restrict__ b1,
                      ushort* __restrict__ out32bf)
{
    __shared__ __align__(16) char hbuf[2][2048];   // [buf][16 rows][64 bf16]
    __shared__ int idxs[16 * 257];                 // [row][t], stride 257

    const int tid  = threadIdx.x;
    const int lane = tid & 63;
    const int w    = tid >> 6;          // unit group
    const int r0   = blockIdx.x * 16;
    const int lrow = lane & 15;
    const int lhi  = lane >> 4;
    const int jcol = w * 16 + lrow;

    bf16x8 bw[16];
    f32x4 bsp[4];
    #pragma unroll
    for (int g = 0; g < 4; ++g) {
        const int col = g * 64 + jcol;
        const float sc = (g == 2) ? 2.f : 1.f;
        const float bv = b[col] * sc;
        bsp[g] = (f32x4){bv, bv, bv, bv};
        #pragma unroll
        for (int s = 0; s < 4; ++s) {
            bf16x8 f;
            #pragma unroll
            for (int i = 0; i < 8; ++i) {
                int k = s * 32 + lhi * 8 + i;
                float v = (k < 64) ? Wx[k * 256 + col] : Wh[(k - 64) * 256 + col];
                f[i] = (short)f2bf(v * sc);
            }
            bw[g * 4 + s] = f;
        }
    }

    bf16x8 bw1[2];
    float b1v = 0.f;
    if (w < 2) {
        const int col = w * 16 + lrow;
        b1v = b1[col];
        #pragma unroll
        for (int s = 0; s < 2; ++s) {
            bf16x8 f;
            #pragma unroll
            for (int i = 0; i < 8; ++i)
                f[i] = (short)f2bf(W1[(s * 32 + lhi * 8 + i) * D1_ + col]);
            bw1[s] = f;
        }
    }

    {
        const int row = tid >> 4, tc = tid & 15;
        #pragma unroll
        for (int k = 0; k < 16; ++k) {
            int t = k * 16 + tc;
            if (t < T_) idxs[row * 257 + t] = idx[(r0 + row) * T_ + t];
        }
        ((float2*)hbuf[0])[tid] = make_float2(0.f, 0.f);
    }
    __syncthreads();

    bf16x8 xe0, xe1, xo0, xo1;
    {
        int iv = idxs[lrow * 257 + 0];
        xe0 = *(const bf16x8*)(emb_bf + iv * 64 + lhi * 8);
        xe1 = *(const bf16x8*)(emb_bf + iv * 64 + 32 + lhi * 8);
        iv = idxs[lrow * 257 + 1];
        xo0 = *(const bf16x8*)(emb_bf + iv * 64 + lhi * 8);
        xo1 = *(const bf16x8*)(emb_bf + iv * 64 + 32 + lhi * 8);
    }

    float cst[4]  = {0.f, 0.f, 0.f, 0.f};

    auto do_step = [&](int t, bf16x8& x0, bf16x8& x1) {
        const int p = t & 1;
        bf16x8 ah2 = *(const bf16x8*)(&hbuf[p][hswz(lrow, lhi * 16)]);
        bf16x8 ah3 = *(const bf16x8*)(&hbuf[p][hswz(lrow, 64 + lhi * 16)]);

        f32x4 z[4];
        #pragma unroll
        for (int g = 0; g < 4; ++g)
            z[g] = __builtin_amdgcn_mfma_f32_16x16x32_bf16(x0, bw[g * 4 + 0], bsp[g], 0, 0, 0);
        #pragma unroll
        for (int g = 0; g < 4; ++g)
            z[g] = __builtin_amdgcn_mfma_f32_16x16x32_bf16(x1, bw[g * 4 + 1], z[g], 0, 0, 0);
        #pragma unroll
        for (int g = 0; g < 4; ++g)
            z[g] = __builtin_amdgcn_mfma_f32_16x16x32_bf16(ah2, bw[g * 4 + 2], z[g], 0, 0, 0);
        #pragma unroll
        for (int g = 0; g < 4; ++g)
            z[g] = __builtin_amdgcn_mfma_f32_16x16x32_bf16(ah3, bw[g * 4 + 3], z[g], 0, 0, 0);

        if (t + 2 < T_) {
            int iv = idxs[lrow * 257 + (t + 2)];
            x0 = *(const bf16x8*)(emb_bf + iv * 64 + lhi * 8);
            x1 = *(const bf16x8*)(emb_bf + iv * 64 + 32 + lhi * 8);
        }

        #pragma unroll
        for (int r = 0; r < 4; ++r) {
            float cn = fast_sigmoid(z[1][r]) * cst[r]
                     + fast_sigmoid(z[0][r]) * fast_tanh_pre(z[2][r]);
            cst[r] = cn;
            float hn = fast_sigmoid(z[3][r]) * fast_tanh(cn);
            const int row = lhi * 4 + r;
            *(ushort*)(&hbuf[p ^ 1][hswz(row, 2 * jcol)]) = f2bf(hn);
        }

        asm volatile("s_waitcnt lgkmcnt(0)\n\ts_barrier" ::: "memory");
    };

    for (int t = 0; t + 1 < T_; t += 2) {
        do_step(t,     xe0, xe1);
        do_step(t + 1, xo0, xo1);
    }
    do_step(T_ - 1, xe0, xe1);

    if (w < 2) {
        bf16x8 e0 = *(const bf16x8*)(&hbuf[1][hswz(lrow, lhi * 16)]);
        bf16x8 e1 = *(const bf16x8*)(&hbuf[1][hswz(lrow, 64 + lhi * 16)]);
        f32x4 zz = (f32x4){b1v, b1v, b1v, b1v};
        zz = __builtin_amdgcn_mfma_f32_16x16x32_bf16(e0, bw1[0], zz, 0, 0, 0);
        zz = __builtin_amdgcn_mfma_f32_16x16x32_bf16(e1, bw1[1], zz, 0, 0, 0);
        #pragma unroll
        for (int r = 0; r < 4; ++r)
            out32bf[(r0 + lhi * 4 + r) * D1_ + w * 16 + lrow] =
                f2bf(fmaxf(zz[r], 0.f));
    }
}

// ---------------------------------------------------------------------------
// Kernel 3: logits = out32 @ W2 + b2, softmax over V, via MFMA.
// REPS: in-kernel idempotent repetition for calibration (bit-exact output).
// ---------------------------------------------------------------------------
template <int PASS, int REPS>
__global__ __launch_bounds__(256)
void head2_mfma_kernel(const ushort* __restrict__ out32bf,
                       const ushort* __restrict__ w2p,
                       const float* __restrict__ b2,
                       float* __restrict__ partial,   // [B][NCHUNK]
                       float* __restrict__ out)
{
    __shared__ float red[4][16];
    __shared__ float sinvs[16];

    const int tid  = threadIdx.x;
    const int lane = tid & 63;
    const int w    = tid >> 6;
    const int lrow = lane & 15;
    const int lhi  = lane >> 4;
    const int r0    = blockIdx.x * 16;
    const int chunk = blockIdx.y;

    for (int rep = 0; rep < REPS; ++rep) {
        if (PASS == 2) {
            if (tid < 16) {
                float s = 0.f;
                #pragma unroll
                for (int c = 0; c < NCHUNK; ++c) s += partial[(r0 + tid) * NCHUNK + c];
                sinvs[tid] = 1.f / s;
            }
            __syncthreads();
        }

        const bf16x8 A = *(const bf16x8*)(out32bf + (r0 + lrow) * D1_ + lhi * 8);

        float sacc[4] = {0.f, 0.f, 0.f, 0.f};
        float si[4];
        if (PASS == 2) {
            #pragma unroll
            for (int r = 0; r < 4; ++r) si[r] = sinvs[lhi * 4 + r];
        }

        const int ct0 = chunk * CT_PER_CHUNK + w * CT_PER_WAVE;
        for (int i = 0; i < CT_PER_WAVE; ++i) {
            const int ct = ct0 + i;
            const bf16x8 Bf = *(const bf16x8*)(w2p + ct * 512 + lane * 8);
            f32x4 z = __builtin_amdgcn_mfma_f32_16x16x32_bf16(A, Bf, (f32x4){0.f, 0.f, 0.f, 0.f}, 0, 0, 0);
            const float b2v = b2[ct * 16 + lrow];
            #pragma unroll
            for (int r = 0; r < 4; ++r) {
                float e = __expf(z[r] + b2v);
                if (PASS == 1) sacc[r] += e;
                else out[(size_t)(r0 + lhi * 4 + r) * V_ + ct * 16 + lrow] = e * si[r];
            }
        }

        if (PASS == 1) {
            #pragma unroll
            for (int r = 0; r < 4; ++r) {
                float v = sacc[r];
                #pragma unroll
                for (int off = 1; off < 16; off <<= 1) v += __shfl_xor(v, off, 16);
                if (lrow == 0) red[w][lhi * 4 + r] = v;
            }
            __syncthreads();
            if (tid < 16)
                partial[(r0 + tid) * NCHUNK + chunk] =
                    red[0][tid] + red[1][tid] + red[2][tid] + red[3][tid];
            __syncthreads();   // red[] reusable next rep
        } else {
            __syncthreads();   // sinvs reusable next rep
        }
    }
}

// ---------------------------------------------------------------------------
extern "C" void kernel_launch(void* const* d_in, const int* in_sizes, int n_in,
                              void* d_out, int out_size, void* d_ws, size_t ws_size,
                              hipStream_t stream)
{
    (void)in_sizes; (void)n_in; (void)out_size; (void)ws_size;

    const int*   idx = (const int*)  d_in[0];
    const float* emb = (const float*)d_in[1];
    const float* Wx  = (const float*)d_in[2];
    const float* Wh  = (const float*)d_in[3];
    const float* bl  = (const float*)d_in[4];
    const float* W1  = (const float*)d_in[5];
    const float* b1  = (const float*)d_in[6];
    const float* W2  = (const float*)d_in[7];
    const float* b2  = (const float*)d_in[8];
    float* out = (float*)d_out;

    float*  ws      = (float*)d_ws;
    ushort* out32bf = (ushort*)ws;                           // 131072 us
    ushort* w2p     = (ushort*)(ws + 65536);                 // 1024000 us
    float*  part    = ws + 65536 + 512000;                   // 40960 f32
    ushort* emb_bf  = (ushort*)(ws + 65536 + 512000 + 40960);  // 2048000 us

    prep_kernel<<<1500, 256, 0, stream>>>(emb, emb_bf, W2, w2p);
    lstm_mfma_kernel<<<256, 256, 0, stream>>>(idx, emb_bf, Wx, Wh, bl, W1, b1, out32bf);

    dim3 g3(B_ / 16, NCHUNK);
    head2_mfma_kernel<1, P1_REPS><<<g3, 256, 0, stream>>>(out32bf, w2p, b2, part, out);
    head2_mfma_kernel<2, P2_REPS><<<g3, 256, 0, stream>>>(out32bf, w2p, b2, part, out);
}

// Round 12
// 381.597 us; speedup vs baseline: 4.0917x; 4.0917x over previous
//
#include <hip/hip_runtime.h>
#include <hip/hip_bf16.h>

#define B_  4096
#define T_  255
#define V_  32000
#define E_  64
#define H_  64
#define D1_ 32

#define NCT           2000   // V/16 col-tiles
#define NCHUNK        10
#define CT_PER_CHUNK  200    // NCT / NCHUNK
#define CT_PER_WAVE   50     // CT_PER_CHUNK / 4 waves

#define LOG2E  1.4426950408889634f

#if __has_builtin(__builtin_amdgcn_exp2f)
#define EXP2F __builtin_amdgcn_exp2f
#else
#define EXP2F exp2f
#endif

typedef __attribute__((ext_vector_type(8))) short bf16x8;   // 8 bf16 = 4 VGPR
typedef __attribute__((ext_vector_type(4))) float f32x4;

__device__ __forceinline__ ushort f2bf(float f) {
    __hip_bfloat16 h = __float2bfloat16(f);   // RNE
    return *reinterpret_cast<ushort*>(&h);
}

// Swizzled byte offset in a [16 rows][64 bf16] (128 B/row) h-tile.
__device__ __forceinline__ int hswz(int row, int colb) {
    return row * 128 + (colb ^ ((row & 7) << 4));
}

// ---------------------------------------------------------------------------
// Kernel 0 (merged): blocks [0,1000): emb fp32->bf16 ; [1000,1500): W2 repack
// prescaled by log2e (softmax exp becomes a single v_exp_f32).
// ---------------------------------------------------------------------------
__global__ __launch_bounds__(256)
void prep_kernel(const float* __restrict__ emb, ushort* __restrict__ emb_bf,
                 const float* __restrict__ W2,  ushort* __restrict__ w2p)
{
    if (blockIdx.x < 1000) {
        int i = blockIdx.x * 256 + threadIdx.x;      // over V*64/8 = 256000
        const float4 a = ((const float4*)emb)[i * 2];
        const float4 b = ((const float4*)emb)[i * 2 + 1];
        ushort t[8] = { f2bf(a.x), f2bf(a.y), f2bf(a.z), f2bf(a.w),
                        f2bf(b.x), f2bf(b.y), f2bf(b.z), f2bf(b.w) };
        *(ushort4*)(&emb_bf[i * 8])     = *(ushort4*)(&t[0]);
        *(ushort4*)(&emb_bf[i * 8 + 4]) = *(ushort4*)(&t[4]);
    } else {
        int t = (blockIdx.x - 1000) * 256 + threadIdx.x;   // over NCT*64
        if (t >= NCT * 64) return;
        int ct = t >> 6, l = t & 63;
        int kbase = (l >> 4) * 8, c = ct * 16 + (l & 15);
        ushort tmp[8];
        #pragma unroll
        for (int i = 0; i < 8; ++i)
            tmp[i] = f2bf(W2[(kbase + i) * V_ + c] * LOG2E);
        *(ushort4*)(&w2p[t * 8])     = *(ushort4*)(&tmp[0]);
        *(ushort4*)(&w2p[t * 8 + 4]) = *(ushort4*)(&tmp[4]);
    }
}

// ===========================================================================
// LSTM, bf16 MFMA. 512 blocks x 8 batch rows (2 blocks/CU = 2 waves/SIMD —
// independent barrier domains interleave each other's stalls). Rows 8-15 of
// every tile are DUPLICATES of 0-7 (idx gather uses lrow&7): no divergence,
// same per-wave instruction count, only the final store is guarded.
// Quad-slot x pipeline: load->use = 4 steps (covers HBM+TLB cold misses).
// Gate weights exp2-prescaled: sigmoid gates by -log2e, g gate by +2log2e,
// so every activation exp is a raw v_exp_f32 (no hidden mul).
// head1 fused as epilogue.
// ===========================================================================
__global__ __launch_bounds__(256, 2)
void lstm_mfma_kernel(const int* __restrict__ idx,
                      const ushort* __restrict__ emb_bf,
                      const float* __restrict__ Wx,
                      const float* __restrict__ Wh,
                      const float* __restrict__ b,
                      const float* __restrict__ W1,
                      const float* __restrict__ b1,
                      ushort* __restrict__ out32bf)
{
    __shared__ __align__(16) char hbuf[2][2048];   // [buf][16 rows][64 bf16]
    __shared__ int idxs[8 * 257];                  // [row][t], stride 257

    const int tid  = threadIdx.x;
    const int lane = tid & 63;
    const int w    = tid >> 6;          // unit group
    const int r0   = blockIdx.x * 8;    // 8 real rows per block
    const int lrow = lane & 15;
    const int lhi  = lane >> 4;
    const int jcol = w * 16 + lrow;

    // persistent B fragments: 4 gates x 4 K-slices (s=0,1: Wx ; s=2,3: Wh)
    // sigmoid gates (0,1,3) scaled by -log2e; tanh gate (2) by +2log2e.
    bf16x8 bw[16];
    f32x4 bsp[4];
    #pragma unroll
    for (int g = 0; g < 4; ++g) {
        const int col = g * 64 + jcol;
        const float sc = (g == 2) ? (2.f * LOG2E) : (-LOG2E);
        const float bv = b[col] * sc;
        bsp[g] = (f32x4){bv, bv, bv, bv};
        #pragma unroll
        for (int s = 0; s < 4; ++s) {
            bf16x8 f;
            #pragma unroll
            for (int i = 0; i < 8; ++i) {
                int k = s * 32 + lhi * 8 + i;
                float v = (k < 64) ? Wx[k * 256 + col] : Wh[(k - 64) * 256 + col];
                f[i] = (short)f2bf(v * sc);
            }
            bw[g * 4 + s] = f;
        }
    }

    // W1 B-frags for the fused head1 epilogue (waves 0,1 only)
    bf16x8 bw1[2];
    float b1v = 0.f;
    if (w < 2) {
        const int col = w * 16 + lrow;
        b1v = b1[col];
        #pragma unroll
        for (int s = 0; s < 2; ++s) {
            bf16x8 f;
            #pragma unroll
            for (int i = 0; i < 8; ++i)
                f[i] = (short)f2bf(W1[(s * 32 + lhi * 8 + i) * D1_ + col]);
            bw1[s] = f;
        }
    }

    {
        const int row = tid >> 5, tc = tid & 31;   // 8 rows x 32 cols
        #pragma unroll
        for (int k = 0; k < 8; ++k) {
            int t = k * 32 + tc;
            if (t < T_) idxs[row * 257 + t] = idx[(r0 + row) * T_ + t];
        }
        ((float2*)hbuf[0])[tid] = make_float2(0.f, 0.f);
    }
    __syncthreads();

    // quad-slot x pipeline (no rotation: true 4-step load->use distance)
    const int grow = lrow & 7;   // gather row (rows 8-15 duplicate 0-7)
    bf16x8 xa0, xa1, xb0, xb1, xc0, xc1, xd0, xd1;
    {
        int iv = idxs[grow * 257 + 0];
        xa0 = *(const bf16x8*)(emb_bf + iv * 64 + lhi * 8);
        xa1 = *(const bf16x8*)(emb_bf + iv * 64 + 32 + lhi * 8);
        iv = idxs[grow * 257 + 1];
        xb0 = *(const bf16x8*)(emb_bf + iv * 64 + lhi * 8);
        xb1 = *(const bf16x8*)(emb_bf + iv * 64 + 32 + lhi * 8);
        iv = idxs[grow * 257 + 2];
        xc0 = *(const bf16x8*)(emb_bf + iv * 64 + lhi * 8);
        xc1 = *(const bf16x8*)(emb_bf + iv * 64 + 32 + lhi * 8);
        iv = idxs[grow * 257 + 3];
        xd0 = *(const bf16x8*)(emb_bf + iv * 64 + lhi * 8);
        xd1 = *(const bf16x8*)(emb_bf + iv * 64 + 32 + lhi * 8);
    }

    float cst[4]  = {0.f, 0.f, 0.f, 0.f};

    auto do_step = [&](int t, bf16x8& x0, bf16x8& x1) {
        const int p = t & 1;
        bf16x8 ah2 = *(const bf16x8*)(&hbuf[p][hswz(lrow, lhi * 16)]);
        bf16x8 ah3 = *(const bf16x8*)(&hbuf[p][hswz(lrow, 64 + lhi * 16)]);

        // z = bias + [x|h] @ W : 4 parallel gate chains, depth 4
        f32x4 z[4];
        #pragma unroll
        for (int g = 0; g < 4; ++g)
            z[g] = __builtin_amdgcn_mfma_f32_16x16x32_bf16(x0, bw[g * 4 + 0], bsp[g], 0, 0, 0);
        #pragma unroll
        for (int g = 0; g < 4; ++g)
            z[g] = __builtin_amdgcn_mfma_f32_16x16x32_bf16(x1, bw[g * 4 + 1], z[g], 0, 0, 0);
        #pragma unroll
        for (int g = 0; g < 4; ++g)
            z[g] = __builtin_amdgcn_mfma_f32_16x16x32_bf16(ah2, bw[g * 4 + 2], z[g], 0, 0, 0);
        #pragma unroll
        for (int g = 0; g < 4; ++g)
            z[g] = __builtin_amdgcn_mfma_f32_16x16x32_bf16(ah3, bw[g * 4 + 3], z[g], 0, 0, 0);

        // reload THIS slot for t+4 (in flight across 4 raw barriers)
        if (t + 4 < T_) {
            int iv = idxs[grow * 257 + (t + 4)];
            x0 = *(const bf16x8*)(emb_bf + iv * 64 + lhi * 8);
            x1 = *(const bf16x8*)(emb_bf + iv * 64 + 32 + lhi * 8);
        }

        // activation (wave-local; z pre-scaled so exp2 is raw v_exp_f32)
        #pragma unroll
        for (int r = 0; r < 4; ++r) {
            float si = __builtin_amdgcn_rcpf(1.f + EXP2F(z[0][r]));
            float sf = __builtin_amdgcn_rcpf(1.f + EXP2F(z[1][r]));
            float tg = 1.f - 2.f * __builtin_amdgcn_rcpf(1.f + EXP2F(z[2][r]));
            float cn = sf * cst[r] + si * tg;
            cst[r] = cn;
            float so = __builtin_amdgcn_rcpf(1.f + EXP2F(z[3][r]));
            float th = 1.f - 2.f * __builtin_amdgcn_rcpf(1.f + EXP2F(cn * (2.f * LOG2E)));
            float hn = so * th;
            const int row = lhi * 4 + r;
            *(ushort*)(&hbuf[p ^ 1][hswz(row, 2 * jcol)]) = f2bf(hn);
        }

        // LDS-only fence + raw barrier (global loads stay in flight)
        asm volatile("s_waitcnt lgkmcnt(0)\n\ts_barrier" ::: "memory");
    };

    for (int t = 0; t + 3 < T_; t += 4) {        // 0..251
        do_step(t,     xa0, xa1);
        do_step(t + 1, xb0, xb1);
        do_step(t + 2, xc0, xc1);
        do_step(t + 3, xd0, xd1);
    }
    do_step(252, xa0, xa1);                      // T_=255 tail
    do_step(253, xb0, xb1);
    do_step(254, xc0, xc1);

    // ---- fused head1: out32 = relu(h(T-1) @ W1 + b1), h from hbuf[1] ----
    if (w < 2) {
        bf16x8 e0 = *(const bf16x8*)(&hbuf[1][hswz(lrow, lhi * 16)]);
        bf16x8 e1 = *(const bf16x8*)(&hbuf[1][hswz(lrow, 64 + lhi * 16)]);
        f32x4 zz = (f32x4){b1v, b1v, b1v, b1v};
        zz = __builtin_amdgcn_mfma_f32_16x16x32_bf16(e0, bw1[0], zz, 0, 0, 0);
        zz = __builtin_amdgcn_mfma_f32_16x16x32_bf16(e1, bw1[1], zz, 0, 0, 0);
        if (lhi < 2) {   // rows 8-15 are duplicates — store real rows only
            #pragma unroll
            for (int r = 0; r < 4; ++r)
                out32bf[(r0 + lhi * 4 + r) * D1_ + w * 16 + lrow] =
                    f2bf(fmaxf(zz[r], 0.f));
        }
    }
}

// ---------------------------------------------------------------------------
// Kernel 3: logits = out32 @ W2 + b2, softmax over V, via MFMA.
// w2p prescaled by log2e; b2 scaled in-kernel -> exp is one v_exp_f32.
// ---------------------------------------------------------------------------
template <int PASS>
__global__ __launch_bounds__(256)
void head2_mfma_kernel(const ushort* __restrict__ out32bf,
                       const ushort* __restrict__ w2p,
                       const float* __restrict__ b2,
                       float* __restrict__ partial,   // [B][NCHUNK]
                       float* __restrict__ out)
{
    __shared__ float red[4][16];
    __shared__ float sinvs[16];

    const int tid  = threadIdx.x;
    const int lane = tid & 63;
    const int w    = tid >> 6;
    const int lrow = lane & 15;
    const int lhi  = lane >> 4;
    const int r0    = blockIdx.x * 16;
    const int chunk = blockIdx.y;

    if (PASS == 2) {
        if (tid < 16) {
            float s = 0.f;
            #pragma unroll
            for (int c = 0; c < NCHUNK; ++c) s += partial[(r0 + tid) * NCHUNK + c];
            sinvs[tid] = 1.f / s;
        }
        __syncthreads();
    }

    const bf16x8 A = *(const bf16x8*)(out32bf + (r0 + lrow) * D1_ + lhi * 8);

    float sacc[4] = {0.f, 0.f, 0.f, 0.f};
    float si[4];
    if (PASS == 2) {
        #pragma unroll
        for (int r = 0; r < 4; ++r) si[r] = sinvs[lhi * 4 + r];
    }

    const int ct0 = chunk * CT_PER_CHUNK + w * CT_PER_WAVE;
    for (int i = 0; i < CT_PER_WAVE; ++i) {
        const int ct = ct0 + i;
        const bf16x8 Bf = *(const bf16x8*)(w2p + ct * 512 + lane * 8);
        f32x4 z = __builtin_amdgcn_mfma_f32_16x16x32_bf16(A, Bf, (f32x4){0.f, 0.f, 0.f, 0.f}, 0, 0, 0);
        const float b2s = b2[ct * 16 + lrow] * LOG2E;
        #pragma unroll
        for (int r = 0; r < 4; ++r) {
            float e = EXP2F(z[r] + b2s);
            if (PASS == 1) sacc[r] += e;
            else out[(size_t)(r0 + lhi * 4 + r) * V_ + ct * 16 + lrow] = e * si[r];
        }
    }

    if (PASS == 1) {
        #pragma unroll
        for (int r = 0; r < 4; ++r) {
            float v = sacc[r];
            #pragma unroll
            for (int off = 1; off < 16; off <<= 1) v += __shfl_xor(v, off, 16);
            if (lrow == 0) red[w][lhi * 4 + r] = v;
        }
        __syncthreads();
        if (tid < 16)
            partial[(r0 + tid) * NCHUNK + chunk] =
                red[0][tid] + red[1][tid] + red[2][tid] + red[3][tid];
    }
}

// ---------------------------------------------------------------------------
extern "C" void kernel_launch(void* const* d_in, const int* in_sizes, int n_in,
                              void* d_out, int out_size, void* d_ws, size_t ws_size,
                              hipStream_t stream)
{
    (void)in_sizes; (void)n_in; (void)out_size; (void)ws_size;

    const int*   idx = (const int*)  d_in[0];
    const float* emb = (const float*)d_in[1];
    const float* Wx  = (const float*)d_in[2];
    const float* Wh  = (const float*)d_in[3];
    const float* bl  = (const float*)d_in[4];
    const float* W1  = (const float*)d_in[5];
    const float* b1  = (const float*)d_in[6];
    const float* W2  = (const float*)d_in[7];
    const float* b2  = (const float*)d_in[8];
    float* out = (float*)d_out;

    float*  ws      = (float*)d_ws;
    ushort* out32bf = (ushort*)ws;                           // 131072 us
    ushort* w2p     = (ushort*)(ws + 65536);                 // 1024000 us
    float*  part    = ws + 65536 + 512000;                   // 40960 f32
    ushort* emb_bf  = (ushort*)(ws + 65536 + 512000 + 40960);  // 2048000 us

    prep_kernel<<<1500, 256, 0, stream>>>(emb, emb_bf, W2, w2p);
    lstm_mfma_kernel<<<B_ / 8, 256, 0, stream>>>(idx, emb_bf, Wx, Wh, bl, W1, b1, out32bf);

    dim3 g3(B_ / 16, NCHUNK);
    head2_mfma_kernel<1><<<g3, 256, 0, stream>>>(out32bf, w2p, b2, part, out);
    head2_mfma_kernel<2><<<g3, 256, 0, stream>>>(out32bf, w2p, b2, part, out);
}

// Round 13
// 336.861 us; speedup vs baseline: 4.6351x; 1.1328x over previous
//
#include <hip/hip_runtime.h>
#include <hip/hip_bf16.h>

#define B_  4096
#define T_  255
#define V_  32000
#define E_  64
#define H_  64
#define D1_ 32

#define NCT           2000   // V/16 col-tiles
#define NCHUNK        10
#define CT_PER_CHUNK  200    // NCT / NCHUNK
#define CT_PER_WAVE   50     // CT_PER_CHUNK / 4 waves

#define LOG2E  1.4426950408889634f

#if __has_builtin(__builtin_amdgcn_exp2f)
#define EXP2F __builtin_amdgcn_exp2f
#else
#define EXP2F exp2f
#endif

typedef __attribute__((ext_vector_type(8))) short bf16x8;   // 8 bf16 = 4 VGPR
typedef __attribute__((ext_vector_type(4))) float f32x4;

__device__ __forceinline__ ushort f2bf(float f) {
    __hip_bfloat16 h = __float2bfloat16(f);   // RNE
    return *reinterpret_cast<ushort*>(&h);
}

// Swizzled byte offset in a [16 rows][64 bf16] (128 B/row) h-tile.
__device__ __forceinline__ int hswz(int row, int colb) {
    return row * 128 + (colb ^ ((row & 7) << 4));
}

// ---------------------------------------------------------------------------
// Kernel 0 (merged prep):
//   blocks [0,1000):    emb fp32 -> bf16 (A-frag gatherable)
//   blocks [1000,1500): W2 repack -> bf16 B-frag-linear, prescaled by log2e
//   blocks [1500,1516): LSTM Wx/Wh -> bf16 B-frag-linear, exp2-prescaled
//     wpack[(((w*4+g)*4+s)*64+lane)*8 + i] = sc(g)*W[k][g*64+w*16+(lane&15)],
//     k = s*32 + (lane>>4)*8 + i ; sc = -log2e (sigmoid gates), +2log2e (g).
//     Lane's 16 B-frags then load as 16 coalesced b128 (kills the 128-scalar
//     scatter prologue that dominated lstm cold time).
// ---------------------------------------------------------------------------
__global__ __launch_bounds__(256)
void prep_kernel(const float* __restrict__ emb, ushort* __restrict__ emb_bf,
                 const float* __restrict__ W2,  ushort* __restrict__ w2p,
                 const float* __restrict__ Wx,  const float* __restrict__ Wh,
                 ushort* __restrict__ wpack)
{
    if (blockIdx.x < 1000) {
        int i = blockIdx.x * 256 + threadIdx.x;      // over V*64/8 = 256000
        const float4 a = ((const float4*)emb)[i * 2];
        const float4 b = ((const float4*)emb)[i * 2 + 1];
        ushort t[8] = { f2bf(a.x), f2bf(a.y), f2bf(a.z), f2bf(a.w),
                        f2bf(b.x), f2bf(b.y), f2bf(b.z), f2bf(b.w) };
        *(ushort4*)(&emb_bf[i * 8])     = *(ushort4*)(&t[0]);
        *(ushort4*)(&emb_bf[i * 8 + 4]) = *(ushort4*)(&t[4]);
    } else if (blockIdx.x < 1500) {
        int t = (blockIdx.x - 1000) * 256 + threadIdx.x;   // over NCT*64
        if (t >= NCT * 64) return;
        int ct = t >> 6, l = t & 63;
        int kbase = (l >> 4) * 8, c = ct * 16 + (l & 15);
        ushort tmp[8];
        #pragma unroll
        for (int i = 0; i < 8; ++i)
            tmp[i] = f2bf(W2[(kbase + i) * V_ + c] * LOG2E);
        *(ushort4*)(&w2p[t * 8])     = *(ushort4*)(&tmp[0]);
        *(ushort4*)(&w2p[t * 8 + 4]) = *(ushort4*)(&tmp[4]);
    } else {
        int t = (blockIdx.x - 1500) * 256 + threadIdx.x;   // over 4*4*4*64=4096
        if (t >= 4096) return;
        int lane = t & 63;
        int s    = (t >> 6) & 3;
        int g    = (t >> 8) & 3;
        int w    = (t >> 10) & 3;
        int col  = g * 64 + w * 16 + (lane & 15);
        float sc = (g == 2) ? (2.f * LOG2E) : (-LOG2E);
        ushort tmp[8];
        #pragma unroll
        for (int i = 0; i < 8; ++i) {
            int k = s * 32 + (lane >> 4) * 8 + i;
            float v = (k < 64) ? Wx[k * 256 + col] : Wh[(k - 64) * 256 + col];
            tmp[i] = f2bf(v * sc);
        }
        *(ushort4*)(&wpack[t * 8])     = *(ushort4*)(&tmp[0]);
        *(ushort4*)(&wpack[t * 8 + 4]) = *(ushort4*)(&tmp[4]);
    }
}

// ===========================================================================
// LSTM, bf16 MFMA — R10 structure (measured best): 256 blocks x 16 rows,
// 4 waves, dual-slot x pipeline, one lgkm-only raw barrier per step,
// fused head1 epilogue. Weights loaded from the B-frag-linear wpack
// (16 coalesced b128 per lane). Activation in exp2 form (weights carry
// the +/-log2e scales; only tanh(c) needs an explicit mul).
// ===========================================================================
__global__ __launch_bounds__(256)
void lstm_mfma_kernel(const int* __restrict__ idx,
                      const ushort* __restrict__ emb_bf,
                      const ushort* __restrict__ wpack,
                      const float* __restrict__ b,
                      const float* __restrict__ W1,
                      const float* __restrict__ b1,
                      ushort* __restrict__ out32bf)
{
    __shared__ __align__(16) char hbuf[2][2048];   // [buf][16 rows][64 bf16]
    __shared__ int idxs[16 * 257];                 // [row][t], stride 257

    const int tid  = threadIdx.x;
    const int lane = tid & 63;
    const int w    = tid >> 6;          // unit group
    const int r0   = blockIdx.x * 16;
    const int lrow = lane & 15;
    const int lhi  = lane >> 4;
    const int jcol = w * 16 + lrow;

    // persistent B fragments — coalesced b128 loads from wpack
    bf16x8 bw[16];
    #pragma unroll
    for (int g = 0; g < 4; ++g)
        #pragma unroll
        for (int s = 0; s < 4; ++s)
            bw[g * 4 + s] = *(const bf16x8*)(wpack + (((w * 4 + g) * 4 + s) * 64 + lane) * 8);

    f32x4 bsp[4];
    #pragma unroll
    for (int g = 0; g < 4; ++g) {
        const float sc = (g == 2) ? (2.f * LOG2E) : (-LOG2E);
        const float bv = b[g * 64 + jcol] * sc;
        bsp[g] = (f32x4){bv, bv, bv, bv};
    }

    // W1 B-frags for the fused head1 epilogue (waves 0,1 only)
    bf16x8 bw1[2];
    float b1v = 0.f;
    if (w < 2) {
        const int col = w * 16 + lrow;
        b1v = b1[col];
        #pragma unroll
        for (int s = 0; s < 2; ++s) {
            bf16x8 f;
            #pragma unroll
            for (int i = 0; i < 8; ++i)
                f[i] = (short)f2bf(W1[(s * 32 + lhi * 8 + i) * D1_ + col]);
            bw1[s] = f;
        }
    }

    {
        const int row = tid >> 4, tc = tid & 15;
        #pragma unroll
        for (int k = 0; k < 16; ++k) {
            int t = k * 16 + tc;
            if (t < T_) idxs[row * 257 + t] = idx[(r0 + row) * T_ + t];
        }
        ((float2*)hbuf[0])[tid] = make_float2(0.f, 0.f);
    }
    __syncthreads();

    // dual-slot x pipeline (no register rotation: true 2-step distance)
    bf16x8 xe0, xe1, xo0, xo1;
    {
        int iv = idxs[lrow * 257 + 0];
        xe0 = *(const bf16x8*)(emb_bf + iv * 64 + lhi * 8);
        xe1 = *(const bf16x8*)(emb_bf + iv * 64 + 32 + lhi * 8);
        iv = idxs[lrow * 257 + 1];
        xo0 = *(const bf16x8*)(emb_bf + iv * 64 + lhi * 8);
        xo1 = *(const bf16x8*)(emb_bf + iv * 64 + 32 + lhi * 8);
    }

    float cst[4]  = {0.f, 0.f, 0.f, 0.f};

    auto do_step = [&](int t, bf16x8& x0, bf16x8& x1) {
        const int p = t & 1;
        bf16x8 ah2 = *(const bf16x8*)(&hbuf[p][hswz(lrow, lhi * 16)]);
        bf16x8 ah3 = *(const bf16x8*)(&hbuf[p][hswz(lrow, 64 + lhi * 16)]);

        // z = bias + [x|h] @ W : 4 parallel gate chains, depth 4
        f32x4 z[4];
        #pragma unroll
        for (int g = 0; g < 4; ++g)
            z[g] = __builtin_amdgcn_mfma_f32_16x16x32_bf16(x0, bw[g * 4 + 0], bsp[g], 0, 0, 0);
        #pragma unroll
        for (int g = 0; g < 4; ++g)
            z[g] = __builtin_amdgcn_mfma_f32_16x16x32_bf16(x1, bw[g * 4 + 1], z[g], 0, 0, 0);
        #pragma unroll
        for (int g = 0; g < 4; ++g)
            z[g] = __builtin_amdgcn_mfma_f32_16x16x32_bf16(ah2, bw[g * 4 + 2], z[g], 0, 0, 0);
        #pragma unroll
        for (int g = 0; g < 4; ++g)
            z[g] = __builtin_amdgcn_mfma_f32_16x16x32_bf16(ah3, bw[g * 4 + 3], z[g], 0, 0, 0);

        // reload THIS slot for t+2 (in flight across 2 raw barriers)
        if (t + 2 < T_) {
            int iv = idxs[lrow * 257 + (t + 2)];
            x0 = *(const bf16x8*)(emb_bf + iv * 64 + lhi * 8);
            x1 = *(const bf16x8*)(emb_bf + iv * 64 + 32 + lhi * 8);
        }

        // activation (wave-local; weights carry the exp2 scales)
        #pragma unroll
        for (int r = 0; r < 4; ++r) {
            float si = __builtin_amdgcn_rcpf(1.f + EXP2F(z[0][r]));
            float sf = __builtin_amdgcn_rcpf(1.f + EXP2F(z[1][r]));
            float tg = 1.f - 2.f * __builtin_amdgcn_rcpf(1.f + EXP2F(z[2][r]));
            float cn = sf * cst[r] + si * tg;
            cst[r] = cn;
            float so = __builtin_amdgcn_rcpf(1.f + EXP2F(z[3][r]));
            float th = 1.f - 2.f * __builtin_amdgcn_rcpf(1.f + EXP2F(cn * (2.f * LOG2E)));
            float hn = so * th;
            const int row = lhi * 4 + r;
            *(ushort*)(&hbuf[p ^ 1][hswz(row, 2 * jcol)]) = f2bf(hn);
        }

        // LDS-only fence + raw barrier (global loads stay in flight)
        asm volatile("s_waitcnt lgkmcnt(0)\n\ts_barrier" ::: "memory");
    };

    for (int t = 0; t + 1 < T_; t += 2) {
        do_step(t,     xe0, xe1);
        do_step(t + 1, xo0, xo1);
    }
    do_step(T_ - 1, xe0, xe1);   // T_=255 odd: tail is an even-slot step

    // ---- fused head1: out32 = relu(h(T-1) @ W1 + b1), h from hbuf[1] ----
    if (w < 2) {
        bf16x8 e0 = *(const bf16x8*)(&hbuf[1][hswz(lrow, lhi * 16)]);
        bf16x8 e1 = *(const bf16x8*)(&hbuf[1][hswz(lrow, 64 + lhi * 16)]);
        f32x4 zz = (f32x4){b1v, b1v, b1v, b1v};
        zz = __builtin_amdgcn_mfma_f32_16x16x32_bf16(e0, bw1[0], zz, 0, 0, 0);
        zz = __builtin_amdgcn_mfma_f32_16x16x32_bf16(e1, bw1[1], zz, 0, 0, 0);
        #pragma unroll
        for (int r = 0; r < 4; ++r)
            out32bf[(r0 + lhi * 4 + r) * D1_ + w * 16 + lrow] =
                f2bf(fmaxf(zz[r], 0.f));
    }
}

// ---------------------------------------------------------------------------
// Kernel 3: logits = out32 @ W2 + b2, softmax over V, via MFMA.
// w2p prescaled by log2e; b2 scaled in-kernel -> exp is one v_exp_f32.
// ---------------------------------------------------------------------------
template <int PASS>
__global__ __launch_bounds__(256)
void head2_mfma_kernel(const ushort* __restrict__ out32bf,
                       const ushort* __restrict__ w2p,
                       const float* __restrict__ b2,
                       float* __restrict__ partial,   // [B][NCHUNK]
                       float* __restrict__ out)
{
    __shared__ float red[4][16];
    __shared__ float sinvs[16];

    const int tid  = threadIdx.x;
    const int lane = tid & 63;
    const int w    = tid >> 6;
    const int lrow = lane & 15;
    const int lhi  = lane >> 4;
    const int r0    = blockIdx.x * 16;
    const int chunk = blockIdx.y;

    if (PASS == 2) {
        if (tid < 16) {
            float s = 0.f;
            #pragma unroll
            for (int c = 0; c < NCHUNK; ++c) s += partial[(r0 + tid) * NCHUNK + c];
            sinvs[tid] = 1.f / s;
        }
        __syncthreads();
    }

    const bf16x8 A = *(const bf16x8*)(out32bf + (r0 + lrow) * D1_ + lhi * 8);

    float sacc[4] = {0.f, 0.f, 0.f, 0.f};
    float si[4];
    if (PASS == 2) {
        #pragma unroll
        for (int r = 0; r < 4; ++r) si[r] = sinvs[lhi * 4 + r];
    }

    const int ct0 = chunk * CT_PER_CHUNK + w * CT_PER_WAVE;
    for (int i = 0; i < CT_PER_WAVE; ++i) {
        const int ct = ct0 + i;
        const bf16x8 Bf = *(const bf16x8*)(w2p + ct * 512 + lane * 8);
        f32x4 z = __builtin_amdgcn_mfma_f32_16x16x32_bf16(A, Bf, (f32x4){0.f, 0.f, 0.f, 0.f}, 0, 0, 0);
        const float b2s = b2[ct * 16 + lrow] * LOG2E;
        #pragma unroll
        for (int r = 0; r < 4; ++r) {
            float e = EXP2F(z[r] + b2s);
            if (PASS == 1) sacc[r] += e;
            else out[(size_t)(r0 + lhi * 4 + r) * V_ + ct * 16 + lrow] = e * si[r];
        }
    }

    if (PASS == 1) {
        #pragma unroll
        for (int r = 0; r < 4; ++r) {
            float v = sacc[r];
            #pragma unroll
            for (int off = 1; off < 16; off <<= 1) v += __shfl_xor(v, off, 16);
            if (lrow == 0) red[w][lhi * 4 + r] = v;
        }
        __syncthreads();
        if (tid < 16)
            partial[(r0 + tid) * NCHUNK + chunk] =
                red[0][tid] + red[1][tid] + red[2][tid] + red[3][tid];
    }
}

// ---------------------------------------------------------------------------
extern "C" void kernel_launch(void* const* d_in, const int* in_sizes, int n_in,
                              void* d_out, int out_size, void* d_ws, size_t ws_size,
                              hipStream_t stream)
{
    (void)in_sizes; (void)n_in; (void)out_size; (void)ws_size;

    const int*   idx = (const int*)  d_in[0];
    const float* emb = (const float*)d_in[1];
    const float* Wx  = (const float*)d_in[2];
    const float* Wh  = (const float*)d_in[3];
    const float* bl  = (const float*)d_in[4];
    const float* W1  = (const float*)d_in[5];
    const float* b1  = (const float*)d_in[6];
    const float* W2  = (const float*)d_in[7];
    const float* b2  = (const float*)d_in[8];
    float* out = (float*)d_out;

    float*  ws      = (float*)d_ws;
    ushort* out32bf = (ushort*)ws;                           // 131072 us
    ushort* w2p     = (ushort*)(ws + 65536);                 // 1024000 us
    float*  part    = ws + 65536 + 512000;                   // 40960 f32
    ushort* emb_bf  = (ushort*)(ws + 65536 + 512000 + 40960);  // 2048000 us
    ushort* wpack   = (ushort*)(ws + 65536 + 512000 + 40960 + 1024000);  // 32768 us

    prep_kernel<<<1516, 256, 0, stream>>>(emb, emb_bf, W2, w2p, Wx, Wh, wpack);
    lstm_mfma_kernel<<<256, 256, 0, stream>>>(idx, emb_bf, wpack, bl, W1, b1, out32bf);

    dim3 g3(B_ / 16, NCHUNK);
    head2_mfma_kernel<1><<<g3, 256, 0, stream>>>(out32bf, w2p, b2, part, out);
    head2_mfma_kernel<2><<<g3, 256, 0, stream>>>(out32bf, w2p, b2, part, out);
}

// Round 14
// 303.929 us; speedup vs baseline: 5.1373x; 1.1084x over previous
//
#include <hip/hip_runtime.h>
#include <hip/hip_bf16.h>

#define B_  4096
#define T_  255
#define V_  32000
#define E_  64
#define H_  64
#define D1_ 32

#define NCT           2000   // V/16 col-tiles
#define NCHUNK        10
#define CT_PER_CHUNK  200    // NCT / NCHUNK
#define CT_PER_WAVE   50     // CT_PER_CHUNK / 4 waves

#define LOG2E  1.4426950408889634f

#if __has_builtin(__builtin_amdgcn_exp2f)
#define EXP2F __builtin_amdgcn_exp2f
#else
#define EXP2F exp2f
#endif

typedef __attribute__((ext_vector_type(8))) short bf16x8;   // 8 bf16 = 4 VGPR
typedef __attribute__((ext_vector_type(4))) float f32x4;

__device__ __forceinline__ ushort f2bf(float f) {
    __hip_bfloat16 h = __float2bfloat16(f);   // RNE
    return *reinterpret_cast<ushort*>(&h);
}

// Swizzled byte offset in a [16 rows][64 bf16] (128 B/row) h-tile.
__device__ __forceinline__ int hswz(int row, int colb) {
    return row * 128 + (colb ^ ((row & 7) << 4));
}

// ---------------------------------------------------------------------------
// Kernel 0 (merged prep):
//   blocks [0,1000):    emb fp32 -> bf16 (A-frag gatherable)
//   blocks [1000,1500): W2 repack -> bf16 B-frag-linear, prescaled by log2e
//   blocks [1500,1516): LSTM Wx/Wh -> bf16 B-frag-linear, exp2-prescaled
// ---------------------------------------------------------------------------
__global__ __launch_bounds__(256)
void prep_kernel(const float* __restrict__ emb, ushort* __restrict__ emb_bf,
                 const float* __restrict__ W2,  ushort* __restrict__ w2p,
                 const float* __restrict__ Wx,  const float* __restrict__ Wh,
                 ushort* __restrict__ wpack)
{
    if (blockIdx.x < 1000) {
        int i = blockIdx.x * 256 + threadIdx.x;      // over V*64/8 = 256000
        const float4 a = ((const float4*)emb)[i * 2];
        const float4 b = ((const float4*)emb)[i * 2 + 1];
        ushort t[8] = { f2bf(a.x), f2bf(a.y), f2bf(a.z), f2bf(a.w),
                        f2bf(b.x), f2bf(b.y), f2bf(b.z), f2bf(b.w) };
        *(ushort4*)(&emb_bf[i * 8])     = *(ushort4*)(&t[0]);
        *(ushort4*)(&emb_bf[i * 8 + 4]) = *(ushort4*)(&t[4]);
    } else if (blockIdx.x < 1500) {
        int t = (blockIdx.x - 1000) * 256 + threadIdx.x;   // over NCT*64
        if (t >= NCT * 64) return;
        int ct = t >> 6, l = t & 63;
        int kbase = (l >> 4) * 8, c = ct * 16 + (l & 15);
        ushort tmp[8];
        #pragma unroll
        for (int i = 0; i < 8; ++i)
            tmp[i] = f2bf(W2[(kbase + i) * V_ + c] * LOG2E);
        *(ushort4*)(&w2p[t * 8])     = *(ushort4*)(&tmp[0]);
        *(ushort4*)(&w2p[t * 8 + 4]) = *(ushort4*)(&tmp[4]);
    } else {
        int t = (blockIdx.x - 1500) * 256 + threadIdx.x;   // over 4*4*4*64=4096
        if (t >= 4096) return;
        int lane = t & 63;
        int s    = (t >> 6) & 3;
        int g    = (t >> 8) & 3;
        int w    = (t >> 10) & 3;
        int col  = g * 64 + w * 16 + (lane & 15);
        float sc = (g == 2) ? (2.f * LOG2E) : (-LOG2E);
        ushort tmp[8];
        #pragma unroll
        for (int i = 0; i < 8; ++i) {
            int k = s * 32 + (lane >> 4) * 8 + i;
            float v = (k < 64) ? Wx[k * 256 + col] : Wh[(k - 64) * 256 + col];
            tmp[i] = f2bf(v * sc);
        }
        *(ushort4*)(&wpack[t * 8])     = *(ushort4*)(&tmp[0]);
        *(ushort4*)(&wpack[t * 8 + 4]) = *(ushort4*)(&tmp[4]);
    }
}

// ===========================================================================
// LSTM, bf16 MFMA — R13 structure; activation reduced to 8 trans ops/elem:
// with Ei=e^-zi, Ef=e^-zf, Eg=e^{2zg}, Eo=e^-zo, Ec=e^{2c} (scales folded
// into the MFMA weights), using sigma(a)*tanh(b) = (Eb-1)*rcp((1+Ea)(1+Eb)):
//   c = c*rcp(1+Ef) + (Eg-1)*rcp((1+Ei)(1+Eg))
//   h = (Ec-1)*rcp((1+Eo)(1+Ec))
// 5 exp2 + 3 rcp (was 5+5). All fp32-safe (products <= ~1e9).
// ===========================================================================
__global__ __launch_bounds__(256)
void lstm_mfma_kernel(const int* __restrict__ idx,
                      const ushort* __restrict__ emb_bf,
                      const ushort* __restrict__ wpack,
                      const float* __restrict__ b,
                      const float* __restrict__ W1,
                      const float* __restrict__ b1,
                      ushort* __restrict__ out32bf)
{
    __shared__ __align__(16) char hbuf[2][2048];   // [buf][16 rows][64 bf16]
    __shared__ int idxs[16 * 257];                 // [row][t], stride 257

    const int tid  = threadIdx.x;
    const int lane = tid & 63;
    const int w    = tid >> 6;          // unit group
    const int r0   = blockIdx.x * 16;
    const int lrow = lane & 15;
    const int lhi  = lane >> 4;
    const int jcol = w * 16 + lrow;

    // persistent B fragments — coalesced b128 loads from wpack
    bf16x8 bw[16];
    #pragma unroll
    for (int g = 0; g < 4; ++g)
        #pragma unroll
        for (int s = 0; s < 4; ++s)
            bw[g * 4 + s] = *(const bf16x8*)(wpack + (((w * 4 + g) * 4 + s) * 64 + lane) * 8);

    f32x4 bsp[4];
    #pragma unroll
    for (int g = 0; g < 4; ++g) {
        const float sc = (g == 2) ? (2.f * LOG2E) : (-LOG2E);
        const float bv = b[g * 64 + jcol] * sc;
        bsp[g] = (f32x4){bv, bv, bv, bv};
    }

    // W1 B-frags for the fused head1 epilogue (waves 0,1 only)
    bf16x8 bw1[2];
    float b1v = 0.f;
    if (w < 2) {
        const int col = w * 16 + lrow;
        b1v = b1[col];
        #pragma unroll
        for (int s = 0; s < 2; ++s) {
            bf16x8 f;
            #pragma unroll
            for (int i = 0; i < 8; ++i)
                f[i] = (short)f2bf(W1[(s * 32 + lhi * 8 + i) * D1_ + col]);
            bw1[s] = f;
        }
    }

    {
        const int row = tid >> 4, tc = tid & 15;
        #pragma unroll
        for (int k = 0; k < 16; ++k) {
            int t = k * 16 + tc;
            if (t < T_) idxs[row * 257 + t] = idx[(r0 + row) * T_ + t];
        }
        ((float2*)hbuf[0])[tid] = make_float2(0.f, 0.f);
    }
    __syncthreads();

    // dual-slot x pipeline (no register rotation: true 2-step distance)
    bf16x8 xe0, xe1, xo0, xo1;
    {
        int iv = idxs[lrow * 257 + 0];
        xe0 = *(const bf16x8*)(emb_bf + iv * 64 + lhi * 8);
        xe1 = *(const bf16x8*)(emb_bf + iv * 64 + 32 + lhi * 8);
        iv = idxs[lrow * 257 + 1];
        xo0 = *(const bf16x8*)(emb_bf + iv * 64 + lhi * 8);
        xo1 = *(const bf16x8*)(emb_bf + iv * 64 + 32 + lhi * 8);
    }

    float cst[4]  = {0.f, 0.f, 0.f, 0.f};

    auto do_step = [&](int t, bf16x8& x0, bf16x8& x1) {
        const int p = t & 1;
        bf16x8 ah2 = *(const bf16x8*)(&hbuf[p][hswz(lrow, lhi * 16)]);
        bf16x8 ah3 = *(const bf16x8*)(&hbuf[p][hswz(lrow, 64 + lhi * 16)]);

        // z = bias + [x|h] @ W : 4 parallel gate chains, depth 4
        f32x4 z[4];
        #pragma unroll
        for (int g = 0; g < 4; ++g)
            z[g] = __builtin_amdgcn_mfma_f32_16x16x32_bf16(x0, bw[g * 4 + 0], bsp[g], 0, 0, 0);
        #pragma unroll
        for (int g = 0; g < 4; ++g)
            z[g] = __builtin_amdgcn_mfma_f32_16x16x32_bf16(x1, bw[g * 4 + 1], z[g], 0, 0, 0);
        #pragma unroll
        for (int g = 0; g < 4; ++g)
            z[g] = __builtin_amdgcn_mfma_f32_16x16x32_bf16(ah2, bw[g * 4 + 2], z[g], 0, 0, 0);
        #pragma unroll
        for (int g = 0; g < 4; ++g)
            z[g] = __builtin_amdgcn_mfma_f32_16x16x32_bf16(ah3, bw[g * 4 + 3], z[g], 0, 0, 0);

        // reload THIS slot for t+2 (in flight across 2 raw barriers)
        if (t + 2 < T_) {
            int iv = idxs[lrow * 257 + (t + 2)];
            x0 = *(const bf16x8*)(emb_bf + iv * 64 + lhi * 8);
            x1 = *(const bf16x8*)(emb_bf + iv * 64 + 32 + lhi * 8);
        }

        // activation, 8-trans form (wave-local)
        #pragma unroll
        for (int r = 0; r < 4; ++r) {
            float Ei = EXP2F(z[0][r]);               // e^-zi
            float Ef = EXP2F(z[1][r]);               // e^-zf
            float Eg = EXP2F(z[2][r]);               // e^{2 zg}
            float Eo = EXP2F(z[3][r]);               // e^-zo
            float ig = (Eg - 1.f) * __builtin_amdgcn_rcpf((1.f + Ei) * (1.f + Eg));
            float cn = cst[r] * __builtin_amdgcn_rcpf(1.f + Ef) + ig;
            cst[r] = cn;
            float Ec = EXP2F(cn * (2.f * LOG2E));    // e^{2c}
            float hn = (Ec - 1.f) * __builtin_amdgcn_rcpf((1.f + Eo) * (1.f + Ec));
            const int row = lhi * 4 + r;
            *(ushort*)(&hbuf[p ^ 1][hswz(row, 2 * jcol)]) = f2bf(hn);
        }

        // LDS-only fence + raw barrier (global loads stay in flight)
        asm volatile("s_waitcnt lgkmcnt(0)\n\ts_barrier" ::: "memory");
    };

    for (int t = 0; t + 1 < T_; t += 2) {
        do_step(t,     xe0, xe1);
        do_step(t + 1, xo0, xo1);
    }
    do_step(T_ - 1, xe0, xe1);   // T_=255 odd: tail is an even-slot step

    // ---- fused head1: out32 = relu(h(T-1) @ W1 + b1), h from hbuf[1] ----
    if (w < 2) {
        bf16x8 e0 = *(const bf16x8*)(&hbuf[1][hswz(lrow, lhi * 16)]);
        bf16x8 e1 = *(const bf16x8*)(&hbuf[1][hswz(lrow, 64 + lhi * 16)]);
        f32x4 zz = (f32x4){b1v, b1v, b1v, b1v};
        zz = __builtin_amdgcn_mfma_f32_16x16x32_bf16(e0, bw1[0], zz, 0, 0, 0);
        zz = __builtin_amdgcn_mfma_f32_16x16x32_bf16(e1, bw1[1], zz, 0, 0, 0);
        #pragma unroll
        for (int r = 0; r < 4; ++r)
            out32bf[(r0 + lhi * 4 + r) * D1_ + w * 16 + lrow] =
                f2bf(fmaxf(zz[r], 0.f));
    }
}

// ---------------------------------------------------------------------------
// Kernel 3: logits = out32 @ W2 + b2, softmax over V, via MFMA.
// w2p prescaled by log2e; b2 scaled in-kernel -> exp is one v_exp_f32.
// ---------------------------------------------------------------------------
template <int PASS>
__global__ __launch_bounds__(256)
void head2_mfma_kernel(const ushort* __restrict__ out32bf,
                       const ushort* __restrict__ w2p,
                       const float* __restrict__ b2,
                       float* __restrict__ partial,   // [B][NCHUNK]
                       float* __restrict__ out)
{
    __shared__ float red[4][16];
    __shared__ float sinvs[16];

    const int tid  = threadIdx.x;
    const int lane = tid & 63;
    const int w    = tid >> 6;
    const int lrow = lane & 15;
    const int lhi  = lane >> 4;
    const int r0    = blockIdx.x * 16;
    const int chunk = blockIdx.y;

    if (PASS == 2) {
        if (tid < 16) {
            float s = 0.f;
            #pragma unroll
            for (int c = 0; c < NCHUNK; ++c) s += partial[(r0 + tid) * NCHUNK + c];
            sinvs[tid] = 1.f / s;
        }
        __syncthreads();
    }

    const bf16x8 A = *(const bf16x8*)(out32bf + (r0 + lrow) * D1_ + lhi * 8);

    float sacc[4] = {0.f, 0.f, 0.f, 0.f};
    float si[4];
    if (PASS == 2) {
        #pragma unroll
        for (int r = 0; r < 4; ++r) si[r] = sinvs[lhi * 4 + r];
    }

    const int ct0 = chunk * CT_PER_CHUNK + w * CT_PER_WAVE;
    #pragma unroll 2
    for (int i = 0; i < CT_PER_WAVE; ++i) {
        const int ct = ct0 + i;
        const bf16x8 Bf = *(const bf16x8*)(w2p + ct * 512 + lane * 8);
        f32x4 z = __builtin_amdgcn_mfma_f32_16x16x32_bf16(A, Bf, (f32x4){0.f, 0.f, 0.f, 0.f}, 0, 0, 0);
        const float b2s = b2[ct * 16 + lrow] * LOG2E;
        #pragma unroll
        for (int r = 0; r < 4; ++r) {
            float e = EXP2F(z[r] + b2s);
            if (PASS == 1) sacc[r] += e;
            else out[(size_t)(r0 + lhi * 4 + r) * V_ + ct * 16 + lrow] = e * si[r];
        }
    }

    if (PASS == 1) {
        #pragma unroll
        for (int r = 0; r < 4; ++r) {
            float v = sacc[r];
            #pragma unroll
            for (int off = 1; off < 16; off <<= 1) v += __shfl_xor(v, off, 16);
            if (lrow == 0) red[w][lhi * 4 + r] = v;
        }
        __syncthreads();
        if (tid < 16)
            partial[(r0 + tid) * NCHUNK + chunk] =
                red[0][tid] + red[1][tid] + red[2][tid] + red[3][tid];
    }
}

// ---------------------------------------------------------------------------
extern "C" void kernel_launch(void* const* d_in, const int* in_sizes, int n_in,
                              void* d_out, int out_size, void* d_ws, size_t ws_size,
                              hipStream_t stream)
{
    (void)in_sizes; (void)n_in; (void)out_size; (void)ws_size;

    const int*   idx = (const int*)  d_in[0];
    const float* emb = (const float*)d_in[1];
    const float* Wx  = (const float*)d_in[2];
    const float* Wh  = (const float*)d_in[3];
    const float* bl  = (const float*)d_in[4];
    const float* W1  = (const float*)d_in[5];
    const float* b1  = (const float*)d_in[6];
    const float* W2  = (const float*)d_in[7];
    const float* b2  = (const float*)d_in[8];
    float* out = (float*)d_out;

    float*  ws      = (float*)d_ws;
    ushort* out32bf = (ushort*)ws;                           // 131072 us
    ushort* w2p     = (ushort*)(ws + 65536);                 // 1024000 us
    float*  part    = ws + 65536 + 512000;                   // 40960 f32
    ushort* emb_bf  = (ushort*)(ws + 65536 + 512000 + 40960);  // 2048000 us
    ushort* wpack   = (ushort*)(ws + 65536 + 512000 + 40960 + 1024000);  // 32768 us

    prep_kernel<<<1516, 256, 0, stream>>>(emb, emb_bf, W2, w2p, Wx, Wh, wpack);
    lstm_mfma_kernel<<<256, 256, 0, stream>>>(idx, emb_bf, wpack, bl, W1, b1, out32bf);

    dim3 g3(B_ / 16, NCHUNK);
    head2_mfma_kernel<1><<<g3, 256, 0, stream>>>(out32bf, w2p, b2, part, out);
    head2_mfma_kernel<2><<<g3, 256, 0, stream>>>(out32bf, w2p, b2, part, out);
}